// Round 1
// baseline (163.554 us; speedup 1.0000x reference)
//
#include <hip/hip_runtime.h>
#include <hip/hip_bf16.h>

// Problem constants
#define Bc 2
#define Nc 6
#define Cc 128
#define Hc 16
#define Wc 44
#define Dc 64
#define HWc (Hc*Wc)          // 704
#define BNc (Bc*Nc)          // 12
#define NRAY (Nc*HWc)        // 4224
#define NPTS (Bc*Nc*Dc*HWc)  // 540672
#define BEV_W 256
#define BEV_H 256
#define BEV_HW (BEV_W*BEV_H) // 65536
#define NSEG (Bc*BEV_HW)     // 131072
#define NSCANB 512           // scan blocks (256 segs each)
#define NGRP (NSEG/16)       // 8192 16-cell output groups
#define GNB 768              // gather-role blocks (3072 waves)
#define GNW (GNB*4)
#define ZNB 256              // zero-role blocks (1024 waves)
#define ZNW (ZNB*4)

// ---------------- workspace layout (bytes) ----------------
#define OFF_KI    0                      // fallback only
#define OFF_DB    512                    // fallback only
#define OFF_CNT   1024                   // int cnt[NSEG]      524288
#define OFF_OFFS  (OFF_CNT  + 524288)    // int offs[NSEG]     524288 (global excl after scanT)
#define OFF_FILL  (OFF_OFFS + 524288)    // (unused in fast path)
#define OFF_BSUM  (OFF_FILL + 524288)    // int bsum[512]
#define OFF_ETOT  (OFF_BSUM + 2048)      // int Etot
#define OFF_E8    (OFF_BSUM + 4096)      // int2 e8[NPTS]      4325376 {ray|seg<<13, w}
#define OFF_FT    (OFF_E8   + 4325376)   // float ft[B][NRAY][128] 4325376
#define WS_NEED   (OFF_FT   + 4325376)
#define OFF_ACC   (OFF_FT   + 4325376)   // now: uint pk[NPTS] (rank<<17|seg) 2162688
#define WS_BIG    (OFF_ACC  + 67108864)
#define OFF_FIDX  OFF_E8
#define OFF_FCNT  OFF_CNT

// ---------------------------------------------------------------------------
// numpy-f32-exact setup of Kinv (per bn) and dbins.
// ---------------------------------------------------------------------------
__device__ __forceinline__ void setup_into(int tid, const float* __restrict__ intr,
                                           const int* __restrict__ p_imgh,
                                           const int* __restrict__ p_imgw,
                                           float* Ki, float* db) {
    if (tid < Dc) {
        double v = 1.0 + (double)tid * (59.0 / 63.0);
        db[tid] = (tid == Dc - 1) ? 60.0f : (float)v;
    }
    if (tid >= BNc) return;
    double img_h = (double)p_imgh[0];
    double img_w = (double)p_imgw[0];
    double scale_x = (double)Wc / (img_w / 16.0);
    double scale_y = (double)Hc / (img_h / 16.0);
    float rs0 = (float)(16.0 / scale_x);
    float rs1 = (float)(16.0 / scale_y);
    float rs2 = 1.0f;
    const float* K = intr + tid * 9;
    float k0 = __fmul_rn(K[0], rs0), k1 = __fmul_rn(K[1], rs0), k2 = __fmul_rn(K[2], rs0);
    float k3 = __fmul_rn(K[3], rs1), k4 = __fmul_rn(K[4], rs1), k5 = __fmul_rn(K[5], rs1);
    float k6 = __fmul_rn(K[6], rs2), k7 = __fmul_rn(K[7], rs2), k8 = __fmul_rn(K[8], rs2);
    float c0 = __fsub_rn(__fmul_rn(k4,k8), __fmul_rn(k5,k7));
    float c1 = __fsub_rn(__fmul_rn(k3,k8), __fmul_rn(k5,k6));
    float c2 = __fsub_rn(__fmul_rn(k3,k7), __fmul_rn(k4,k6));
    float det = __fadd_rn(__fsub_rn(__fmul_rn(k0,c0), __fmul_rn(k1,c1)), __fmul_rn(k2,c2));
    float* o = Ki + tid * 9;
    o[0] = __fdiv_rn(c0, det);
    o[1] = __fdiv_rn(__fsub_rn(__fmul_rn(k2,k7), __fmul_rn(k1,k8)), det);
    o[2] = __fdiv_rn(__fsub_rn(__fmul_rn(k1,k5), __fmul_rn(k2,k4)), det);
    o[3] = __fdiv_rn(__fsub_rn(__fmul_rn(k5,k6), __fmul_rn(k3,k8)), det);
    o[4] = __fdiv_rn(__fsub_rn(__fmul_rn(k0,k8), __fmul_rn(k2,k6)), det);
    o[5] = __fdiv_rn(__fsub_rn(__fmul_rn(k2,k3), __fmul_rn(k0,k5)), det);
    o[6] = __fdiv_rn(c2, det);
    o[7] = __fdiv_rn(__fsub_rn(__fmul_rn(k1,k6), __fmul_rn(k0,k7)), det);
    o[8] = __fdiv_rn(__fsub_rn(__fmul_rn(k0,k4), __fmul_rn(k1,k3)), det);
}

__global__ void k_setup(const float* __restrict__ intr, const float* __restrict__ extr,
                        const int* __restrict__ p_imgh, const int* __restrict__ p_imgw,
                        float* __restrict__ Ki, float* __restrict__ db) {
    setup_into(threadIdx.x, intr, p_imgh, p_imgw, Ki, db);
}

// ---------------------------------------------------------------------------
// numpy-f32-exact classify: point gid -> BEV cell (or -1)
// ---------------------------------------------------------------------------
__device__ __forceinline__ int classify_point(int gid, const float* Ki_all,
                                              const float* db, const float* extr) {
    int p   = gid % HWc;
    int tmp = gid / HWc;
    int d   = tmp % Dc;
    int bn  = tmp / Dc;
    int w = p % Wc, h = p / Wc;
    float dd = db[d];
    float ud = __fmul_rn((float)w, dd);
    float vd = __fmul_rn((float)h, dd);
    const float* Ki = Ki_all + bn * 9;
    float pcx = fmaf(Ki[2], dd, fmaf(Ki[1], vd, __fmul_rn(Ki[0], ud)));
    float pcy = fmaf(Ki[5], dd, fmaf(Ki[4], vd, __fmul_rn(Ki[3], ud)));
    float pcz = fmaf(Ki[8], dd, fmaf(Ki[7], vd, __fmul_rn(Ki[6], ud)));
    const float* E = extr + bn * 16;
    float px = __fadd_rn(fmaf(E[2],  pcz, fmaf(E[1], pcy, __fmul_rn(E[0], pcx))), E[3]);
    float py = __fadd_rn(fmaf(E[6],  pcz, fmaf(E[5], pcy, __fmul_rn(E[4], pcx))), E[7]);
    float pz = __fadd_rn(fmaf(E[10], pcz, fmaf(E[9], pcy, __fmul_rn(E[8], pcx))), E[11]);
    float fx = __fdiv_rn(__fsub_rn(px, -51.2f), 0.4f);
    float fy = __fdiv_rn(__fsub_rn(py, -51.2f), 0.4f);
    int xi = (int)fx;
    int yi = (int)fy;
    bool valid = (xi >= 0) && (xi < BEV_W) && (yi >= 0) && (yi < BEV_H)
              && (pz >= -5.0f) && (pz <= 3.0f);
    return valid ? (yi * BEV_W + xi) : -1;
}

// ---------------------------------------------------------------------------
// bsum scan helper (proven rounds 11/12/15) — now used ONLY by k_scanT.
// ---------------------------------------------------------------------------
__device__ __forceinline__ void scan_bsum(int tid, const int* __restrict__ bsum,
                                          int* sB, int* su, int* pEtotS) {
    int2 v2 = ((const int2*)bsum)[tid];
    int s = v2.x + v2.y;
    su[tid] = s;
    __syncthreads();
    for (int st = 1; st < 256; st <<= 1) {
        int t2 = (tid >= st) ? su[tid - st] : 0;
        __syncthreads();
        su[tid] += t2;
        __syncthreads();
    }
    int base = su[tid] - s;
    sB[2 * tid]     = base;
    sB[2 * tid + 1] = base + v2.x;
    if (tid == 255) *pEtotS = base + s;
    __syncthreads();
}

__device__ __forceinline__ unsigned long long lanemask_le(int lane) {
    return (lane == 63) ? ~0ull : ((1ull << (lane + 1)) - 1ull);
}

// ---------------------------------------------------------------------------
// Kernel A: count (+ fused setup, + fused transpose in first 528 blocks).
// NEW: the wave-aggregated atomic's RETURN value gives every point its rank
// within its cell; pack (rank<<17 | seg) into pk so k_fill needs no second
// classify pass, no atomics and no scan.
// ---------------------------------------------------------------------------
__global__ __launch_bounds__(256) void k_count(const float* __restrict__ intr,
                                               const float* __restrict__ extr,
                                               const int* __restrict__ p_imgh,
                                               const int* __restrict__ p_imgw,
                                               const float* __restrict__ feat,
                                               int* __restrict__ cntArr,
                                               unsigned* __restrict__ pk,
                                               float* __restrict__ ft) {
    __shared__ float sKi[BNc * 9];
    __shared__ float sDb[Dc];
    __shared__ float buf[Cc * 17];
    int tid = threadIdx.x;
    setup_into(tid, intr, p_imgh, p_imgw, sKi, sDb);
    __syncthreads();
    int gid = blockIdx.x * 256 + tid;      // grid = NPTS/256 exactly
    int cell = classify_point(gid, sKi, sDb, extr);
    {
        int lane = tid & 63;
        int b = gid / (Nc * Dc * HWc);
        int seg = b * BEV_HW + cell;
        int key = (cell >= 0) ? seg : -1;
        int pkey = __shfl_up(key, 1);
        bool bnd = (lane == 0) || (key != pkey);
        unsigned long long bm = __ballot(bnd);
        int base = 0;
        if (key >= 0 && bnd) {
            unsigned long long rest = (lane == 63) ? 0ull : (bm >> (lane + 1));
            int runlen = (rest != 0ull) ? __ffsll((long long)rest) : (64 - lane);
            base = atomicAdd(&cntArr[seg], runlen);           // returns run's base rank
        }
        int headLane = 63 - __clzll(bm & lanemask_le(lane));
        int rbase = __shfl(base, headLane);
        pk[gid] = (key >= 0)
                ? ((unsigned)seg | ((unsigned)(rbase + (lane - headLane)) << 17))
                : 0xFFFFFFFFu;
    }
    if (blockIdx.x < BNc * (HWc / 16)) {
        int bn   = blockIdx.x / (HWc / 16);
        int tile = blockIdx.x % (HWc / 16);
        const float* fb = feat + (size_t)bn * Cc * HWc + tile * 16;
        for (int i = tid; i < Cc * 16; i += 256) {
            int c = i >> 4, hw = i & 15;
            buf[c * 17 + hw] = fb[c * HWc + hw];
        }
        __syncthreads();
        float* obt = ft + ((size_t)bn * HWc + tile * 16) * Cc;
        for (int i = tid; i < 16 * Cc; i += 256) {
            int r = i >> 7, ch = i & 127;
            obt[(size_t)r * Cc + ch] = buf[ch * 17 + r];
        }
    }
}

// ---------------------------------------------------------------------------
// Kernel B1: block-local exclusive scan (512 x 256).
// ---------------------------------------------------------------------------
__global__ __launch_bounds__(256) void k_scanB(const int* __restrict__ cntArr,
                                               int* __restrict__ offs,
                                               int* __restrict__ bsum) {
    __shared__ int su[256];
    int tid = threadIdx.x;
    int g = blockIdx.x * 256 + tid;
    int v = cntArr[g];
    su[tid] = v;
    __syncthreads();
    for (int st = 1; st < 256; st <<= 1) {
        int t2 = (tid >= st) ? su[tid - st] : 0;
        __syncthreads();
        su[tid] += t2;
        __syncthreads();
    }
    offs[g] = su[tid] - v;
    if (tid == 255) bsum[blockIdx.x] = su[255];
}

// ---------------------------------------------------------------------------
// Kernel B2: globalize — offs[g] += prefix(bsum up to my scan-block); Etot.
// Done ONCE here so fill/gather never re-run the 512-wide LDS scan per block.
// ---------------------------------------------------------------------------
__global__ __launch_bounds__(256) void k_scanT(int* __restrict__ offs,
                                               const int* __restrict__ bsum,
                                               int* __restrict__ EtotG) {
    __shared__ int sB[NSCANB];
    __shared__ int su[256];
    __shared__ int sE;
    int tid = threadIdx.x;
    scan_bsum(tid, bsum, sB, su, &sE);
    int add = sB[blockIdx.x];
    int g = blockIdx.x * 256 + tid;
    offs[g] += add;
    if (blockIdx.x == 0 && tid == 0) *EtotG = sE;
}

// ---------------------------------------------------------------------------
// Kernel C: placement — pure streaming now (no classify, no atomics, no scan).
// pos = offs_global[seg] + rank. Runs write mostly-contiguous slots.
// ---------------------------------------------------------------------------
__global__ __launch_bounds__(256) void k_fill(const unsigned* __restrict__ pk,
                                              const float* __restrict__ depth,
                                              const int* __restrict__ offs,
                                              int2* __restrict__ e8) {
    int gid = blockIdx.x * 256 + threadIdx.x;
    unsigned v = pk[gid];
    if (v == 0xFFFFFFFFu) return;
    int seg  = (int)(v & (unsigned)(NSEG - 1));   // 17 bits
    int rank = (int)(v >> 17);
    int pos  = offs[seg] + rank;
    int p  = gid % HWc;
    int bn = gid / (Dc * HWc);
    int ray = (bn % Nc) * HWc + p;
    e8[pos] = make_int2(ray | (seg << 13), __float_as_int(depth[gid]));
}

// ---------------------------------------------------------------------------
// Flush one 16-cell output group from the per-wave LDS window directly to
// out[b][c][cell], normalized. noinline: called from 8 unrolled sites but
// taken only on group transitions (~1 per 16 cells).
// win stride 132 floats: banks (4g+c)&31 -> worst 2-way (free).
// ---------------------------------------------------------------------------
__device__ __noinline__ void flush_group(const float* winw, const float* sNw,
                                         float* __restrict__ out,
                                         unsigned mask, int g16, int lane) {
    asm volatile("s_waitcnt lgkmcnt(0)" ::: "memory");   // ds_writes from caller drained
    int b = g16 >> 12;                    // 4096 groups per batch
    int cell0 = (g16 & 4095) << 4;
    float* ob = out + (size_t)b * Cc * BEV_HW + cell0;
    int g = lane & 15, cq = lane >> 4;    // 4 channels x 16 cells per iteration
    bool own = (mask >> g) & 1u;
    float inv = __fdiv_rn(1.0f, __fadd_rn(sNw[g], 1e-5f));
    #pragma unroll 4
    for (int c4 = 0; c4 < Cc; c4 += 4) {
        int c = c4 + cq;
        if (own) ob[(size_t)c * BEV_HW + g] = __fmul_rn(winw[g * 132 + c], inv);
    }
}

// per-entry step: accumulate; on cell change close cell into window (the wave
// owns the WHOLE cell, so segN == cnt[seg] -> local normalization); on group
// change flush window to out. All control values are wave-uniform.
#define GF_STEP(EE, FF) do {                                                    \
    int sg_ = (EE).x >> 13;                                                     \
    if (sg_ != curc) {                                                          \
        if (curc >= 0) {                                                        \
            *(float2*)&winw[(curc & 15) * 132 + 2 * lane] = a;                  \
            if (lane == 0) sNw[curc & 15] = (float)segN;                        \
            mask |= 1u << (curc & 15);                                          \
            if ((sg_ >> 4) != (curc >> 4)) {                                    \
                flush_group(winw, sNw, out, mask, curc >> 4, lane);             \
                mask = 0;                                                       \
            }                                                                   \
        }                                                                       \
        curc = sg_; a.x = 0.f; a.y = 0.f; segN = 0;                             \
    }                                                                           \
    segN++;                                                                     \
    float ww_ = __int_as_float((EE).y);                                         \
    a.x = fmaf(ww_, (FF).x, a.x);                                               \
    a.y = fmaf(ww_, (FF).y, a.y);                                               \
} while (0)

// ---------------------------------------------------------------------------
// Kernel D: FUSED gather + finish. Entry-parallel ownership decomposition
// (proven r15) but accumulators flow through a per-wave 16-cell LDS window
// straight to out — the 67 MB acc round-trip is gone. Blocks >= GNB are
// zero-role: they write zeros to cnt==0 cells (disjoint from gather writes).
// ---------------------------------------------------------------------------
__global__ __launch_bounds__(256) void k_gatherF(const float2* __restrict__ ft2,
                                                 const int2* __restrict__ e8,
                                                 const int* __restrict__ cntArr,
                                                 const int* __restrict__ offs,
                                                 const int* __restrict__ EtotG,
                                                 float* __restrict__ out) {
    __shared__ float win[4][16 * 132];
    __shared__ float sN[4][16];
    int tid = threadIdx.x;
    int w = tid >> 6, lane = tid & 63;

    if (blockIdx.x >= GNB) {
        // ---- zero-role: fill empty cells of out ----
        int zwid = (blockIdx.x - GNB) * 4 + w;
        int g = lane & 15, cq = lane >> 4;
        for (int g16 = zwid; g16 < NGRP; g16 += ZNW) {
            int n = (lane < 16) ? cntArr[(g16 << 4) + lane] : 1;
            unsigned long long bz = __ballot(n == 0);
            unsigned em = (unsigned)bz & 0xFFFFu;
            if (em == 0) continue;
            int b = g16 >> 12;
            int cell0 = (g16 & 4095) << 4;
            float* ob = out + (size_t)b * Cc * BEV_HW + cell0;
            bool own = (em >> g) & 1u;
            #pragma unroll 4
            for (int c4 = 0; c4 < Cc; c4 += 4) {
                if (own) ob[(size_t)(c4 + cq) * BEV_HW + g] = 0.f;
            }
        }
        return;
    }

    // ---- gather-role ----
    int Etot = *EtotG;
    int wid  = blockIdx.x * 4 + w;
    int WCH  = (Etot + GNW - 1) / GNW;
    if (WCH <= 0) return;
    int start = wid * WCH;
    if (start >= Etot) return;
    int end = start + WCH; if (end > Etot) end = Etot;
    int k0 = 0;
    if (start > 0) {
        int segP = e8[start - 1].x >> 13;
        k0 = offs[segP] + cntArr[segP];          // end of segP's run (offs is global now)
        if (k0 >= end) return;                   // no cell starts here
    }
    int segE = e8[end - 1].x >> 13;
    int kend = offs[segE] + cntArr[segE];        // extend thru straddler
    int total = kend - k0;

    float* winw = win[w];
    float* sNw  = sN[w];
    float2 a = make_float2(0.f, 0.f);
    int curc = -1;
    int segN = 0;
    unsigned mask = 0;

    const int U = 8;
    int nb = total / U;
    if (nb > 0) {
        int2 e[U];
        #pragma unroll
        for (int u = 0; u < U; u++) e[u] = e8[k0 + u];
        for (int gI = 0; gI < nb; gI++) {
            float2 f[U];
            #pragma unroll
            for (int u = 0; u < U; u++) {
                int sx = e[u].x;
                f[u] = ft2[((size_t)((sx >> 29) * NRAY) + (sx & 8191)) * 64 + lane];
            }
            int2 en[U];
            if (gI + 1 < nb) {
                #pragma unroll
                for (int u = 0; u < U; u++) en[u] = e8[k0 + (gI + 1) * U + u];
            } else {
                #pragma unroll
                for (int u = 0; u < U; u++) en[u] = e[u];
            }
            #pragma unroll
            for (int u = 0; u < U; u++) GF_STEP(e[u], f[u]);
            #pragma unroll
            for (int u = 0; u < U; u++) e[u] = en[u];
        }
    }
    for (int j = nb * U; j < total; j++) {
        int2 ee = e8[k0 + j];
        int sx = ee.x;
        float2 f = ft2[((size_t)((sx >> 29) * NRAY) + (sx & 8191)) * 64 + lane];
        GF_STEP(ee, f);
    }
    if (curc >= 0) {
        *(float2*)&winw[(curc & 15) * 132 + 2 * lane] = a;
        if (lane == 0) sNw[curc & 15] = (float)segN;
        mask |= 1u << (curc & 15);
        flush_group(winw, sNw, out, mask, curc >> 4, lane);
    }
}

// ======================= fallback (round-2 proven) ==========================
__global__ __launch_bounds__(256) void k_classifyF(const float* __restrict__ Ki_all,
                                                   const float* __restrict__ db,
                                                   const float* __restrict__ extr,
                                                   int* __restrict__ idxT,
                                                   float* __restrict__ cnt) {
    int gid = blockIdx.x * 256 + threadIdx.x;
    if (gid >= NPTS) return;
    int cell = classify_point(gid, Ki_all, db, extr);
    idxT[gid] = cell;
    if (cell >= 0) {
        int b = gid / (Nc * Dc * HWc);
        atomicAdd(&cnt[b * BEV_HW + cell], 1.0f);
    }
}

__global__ __launch_bounds__(256) void k_scatterF(const float* __restrict__ feat,
                                                  const float* __restrict__ depth,
                                                  const int* __restrict__ idxT,
                                                  float* __restrict__ out) {
    __shared__ float s_dw[HWc];
    __shared__ int   s_idx[HWc];
    int blk = blockIdx.x;
    int bn  = blk / Dc;
    int b   = bn / Nc;
    int tid = threadIdx.x;
    const float* dp = depth + (size_t)blk * HWc;
    const int*   ip = idxT  + (size_t)blk * HWc;
    for (int p = tid; p < HWc; p += 256) { s_dw[p] = dp[p]; s_idx[p] = ip[p]; }
    __syncthreads();
    const float* fb = feat + (size_t)bn * Cc * HWc;
    float*       ob = out  + (size_t)b  * Cc * BEV_HW;
    for (int c = 0; c < Cc; c++) {
        const float* f = fb + (size_t)c * HWc;
        float*       o = ob + (size_t)c * BEV_HW;
        for (int p = tid; p < HWc; p += 256) {
            int cell = s_idx[p];
            if (cell >= 0) atomicAdd(&o[cell], __fmul_rn(f[p], s_dw[p]));
        }
    }
}

__global__ __launch_bounds__(256) void k_normF(float* __restrict__ out,
                                               const float* __restrict__ cnt) {
    int i = blockIdx.x * 256 + threadIdx.x;
    const int total = Bc * Cc * BEV_HW / 4;
    if (i >= total) return;
    int q = i % (BEV_HW / 4);
    int b = i / (Cc * BEV_HW / 4);
    float4 v = ((float4*)out)[i];
    float4 cv = ((const float4*)cnt)[b * (BEV_HW / 4) + q];
    v.x = __fdiv_rn(v.x, __fadd_rn(cv.x, 1e-5f));
    v.y = __fdiv_rn(v.y, __fadd_rn(cv.y, 1e-5f));
    v.z = __fdiv_rn(v.z, __fadd_rn(cv.z, 1e-5f));
    v.w = __fdiv_rn(v.w, __fadd_rn(cv.w, 1e-5f));
    ((float4*)out)[i] = v;
}

// ===========================================================================
extern "C" void kernel_launch(void* const* d_in, const int* in_sizes, int n_in,
                              void* d_out, int out_size, void* d_ws, size_t ws_size,
                              hipStream_t stream) {
    const float* feat  = (const float*)d_in[0];
    const float* depth = (const float*)d_in[1];
    const float* intr  = (const float*)d_in[2];
    const float* extr  = (const float*)d_in[3];
    const int*   imh   = (const int*)d_in[4];
    const int*   imw   = (const int*)d_in[5];
    float* out = (float*)d_out;
    char*  ws  = (char*)d_ws;

    if (ws_size >= (size_t)WS_BIG) {
        int*      cntA  = (int*)(ws + OFF_CNT);
        int*      offs  = (int*)(ws + OFF_OFFS);
        int*      bsum  = (int*)(ws + OFF_BSUM);
        int*      EtotG = (int*)(ws + OFF_ETOT);
        int2*     e8    = (int2*)(ws + OFF_E8);
        float*    ft    = (float*)(ws + OFF_FT);
        unsigned* pk    = (unsigned*)(ws + OFF_ACC);

        hipMemsetAsync(cntA, 0, (size_t)NSEG * sizeof(int), stream);
        k_count<<<NPTS / 256, 256, 0, stream>>>(intr, extr, imh, imw, feat, cntA, pk, ft);
        k_scanB<<<NSCANB, 256, 0, stream>>>(cntA, offs, bsum);
        k_scanT<<<NSCANB, 256, 0, stream>>>(offs, bsum, EtotG);
        k_fill<<<NPTS / 256, 256, 0, stream>>>(pk, depth, offs, e8);
        k_gatherF<<<GNB + ZNB, 256, 0, stream>>>((const float2*)ft, e8, cntA, offs, EtotG, out);
    } else {
        float* Ki   = (float*)(ws + OFF_KI);
        float* db   = (float*)(ws + OFF_DB);
        int*   idxT = (int*)(ws + OFF_FIDX);
        float* cnt  = (float*)(ws + OFF_FCNT);
        hipMemsetAsync(out, 0, (size_t)out_size * sizeof(float), stream);
        hipMemsetAsync(cnt, 0, (size_t)Bc * BEV_HW * sizeof(float), stream);
        k_setup<<<1, 64, 0, stream>>>(intr, extr, imh, imw, Ki, db);
        k_classifyF<<<(NPTS + 255) / 256, 256, 0, stream>>>(Ki, db, extr, idxT, cnt);
        k_scatterF<<<Bc * Nc * Dc, 256, 0, stream>>>(feat, depth, idxT, out);
        k_normF<<<(Bc * Cc * BEV_HW / 4 + 255) / 256, 256, 0, stream>>>(out, cnt);
    }
}